// Round 1
// baseline (386.023 us; speedup 1.0000x reference)
//
#include <hip/hip_runtime.h>
#include <math.h>

#define LOG2E 1.44269504088896340736f

// fused layout per batch row: [sentence(768) | scene_context(768) | speaker_context(768)]
// final layout per batch row: [z(2304) | sentence_shared(512) | scene_shared(512) | speaker_shared(512)]

__global__ __launch_bounds__(256) void attn_small_kernel(
    const float* __restrict__ sentence,
    const float* __restrict__ target,
    const float* __restrict__ other,
    const float* __restrict__ scene_desc,
    const float* __restrict__ scene_sent,
    float* __restrict__ fused)
{
    const int b = blockIdx.x;
    const int part = blockIdx.y;   // 0: copy sentence, 1: scene ctx, 2: speaker ctx
    const int tid = threadIdx.x;

    if (part == 0) {
        for (int i = tid; i < 768; i += 256)
            fused[b * 2304 + i] = sentence[b * 768 + i];
        return;
    }

    __shared__ float kb[768];   // k * log2(e)
    __shared__ float vb[768];   // v
    const float* qp;
    const float* kp;
    const float* vp;
    if (part == 1) {            // scene_context = attn(q=scene_sent, k=scene_sent, v=scene_desc)
        qp = scene_sent + b * 768; kp = scene_sent + b * 768; vp = scene_desc + b * 768;
    } else {                    // speaker_context = attn(q=other, k=target, v=target)
        qp = other + b * 768;      kp = target + b * 768;     vp = target + b * 768;
    }
    for (int i = tid; i < 768; i += 256) {
        kb[i] = kp[i] * LOG2E;
        vb[i] = vp[i];
    }
    __syncthreads();

    float* out = fused + b * 2304 + part * 768;
    #pragma unroll
    for (int j = 0; j < 3; ++j) {
        const int s = tid + j * 256;
        const float q = qp[s];
        float n0 = 0.f, n1 = 0.f, n2 = 0.f, n3 = 0.f;
        float d0 = 0.f, d1 = 0.f, d2 = 0.f, d3 = 0.f;
        for (int t = 0; t < 768; t += 4) {
            float e0 = __builtin_amdgcn_exp2f(q * kb[t + 0]); n0 += e0 * vb[t + 0]; d0 += e0;
            float e1 = __builtin_amdgcn_exp2f(q * kb[t + 1]); n1 += e1 * vb[t + 1]; d1 += e1;
            float e2 = __builtin_amdgcn_exp2f(q * kb[t + 2]); n2 += e2 * vb[t + 2]; d2 += e2;
            float e3 = __builtin_amdgcn_exp2f(q * kb[t + 3]); n3 += e3 * vb[t + 3]; d3 += e3;
        }
        out[s] = ((n0 + n1) + (n2 + n3)) / ((d0 + d1) + (d2 + d3));
    }
}

__global__ __launch_bounds__(256) void attn_fused_kernel(
    const float* __restrict__ fused,
    float* __restrict__ final_)
{
    const int b = blockIdx.x;
    const int gy = blockIdx.y;     // row group: 9 groups of 256 rows
    const int tid = threadIdx.x;

    __shared__ float fb[2304];     // f * log2(e)  (exponent operand)
    __shared__ float vb[2304];     // f raw        (value operand)
    const float* f = fused + b * 2304;
    for (int i = tid; i < 2304; i += 256) {
        float x = f[i];
        vb[i] = x;
        fb[i] = x * LOG2E;
    }
    __syncthreads();

    const int s = gy * 256 + tid;
    const float q = vb[s];
    float n0 = 0.f, n1 = 0.f, n2 = 0.f, n3 = 0.f;
    float d0 = 0.f, d1 = 0.f, d2 = 0.f, d3 = 0.f;
    for (int t = 0; t < 2304; t += 4) {
        float e0 = __builtin_amdgcn_exp2f(q * fb[t + 0]); n0 += e0 * vb[t + 0]; d0 += e0;
        float e1 = __builtin_amdgcn_exp2f(q * fb[t + 1]); n1 += e1 * vb[t + 1]; d1 += e1;
        float e2 = __builtin_amdgcn_exp2f(q * fb[t + 2]); n2 += e2 * vb[t + 2]; d2 += e2;
        float e3 = __builtin_amdgcn_exp2f(q * fb[t + 3]); n3 += e3 * vb[t + 3]; d3 += e3;
    }
    final_[b * 3840 + s] = ((n0 + n1) + (n2 + n3)) / ((d0 + d1) + (d2 + d3));
}

__global__ __launch_bounds__(512) void shared_proj_kernel(
    const float* __restrict__ fused,
    const float* __restrict__ Ws,   // [768, 512]
    const float* __restrict__ bs,   // [512]
    float* __restrict__ final_)
{
    const int b = blockIdx.x;
    const int p = blockIdx.y;       // 0: sentence, 1: scene_ctx, 2: speaker_ctx
    const int tid = threadIdx.x;    // output column, 512 threads

    __shared__ float xb[768];
    const float* x = fused + b * 2304 + p * 768;
    for (int i = tid; i < 768; i += 512) xb[i] = x[i];
    __syncthreads();

    float acc = bs[tid];
    #pragma unroll 4
    for (int k = 0; k < 768; ++k)
        acc += xb[k] * Ws[k * 512 + tid];
    final_[b * 3840 + 2304 + p * 512 + tid] = acc;
}

__global__ __launch_bounds__(256) void mlp_kernel(
    const float* __restrict__ final_,
    const float* __restrict__ W1,   // [3840, 256]
    const float* __restrict__ b1,   // [256]
    const float* __restrict__ W2,   // [256, 7]
    const float* __restrict__ b2,   // [7]
    float* __restrict__ out)        // [32, 7]
{
    const int b = blockIdx.x;
    const int tid = threadIdx.x;    // output column of h, 256 threads

    __shared__ float fb[3840];
    __shared__ float hb[256];
    const float* f = final_ + b * 3840;
    for (int i = tid; i < 3840; i += 256) fb[i] = f[i];
    __syncthreads();

    float acc = b1[tid];
    #pragma unroll 4
    for (int k = 0; k < 3840; ++k)
        acc += fb[k] * W1[k * 256 + tid];
    hb[tid] = fmaxf(acc, 0.f);
    __syncthreads();

    if (tid < 7) {
        float a = b2[tid];
        for (int c = 0; c < 256; ++c)
            a += hb[c] * W2[c * 7 + tid];
        out[b * 7 + tid] = 1.f / (1.f + __expf(-a));
    }
}

extern "C" void kernel_launch(void* const* d_in, const int* in_sizes, int n_in,
                              void* d_out, int out_size, void* d_ws, size_t ws_size,
                              hipStream_t stream) {
    const float* sentence   = (const float*)d_in[0];
    const float* target     = (const float*)d_in[1];
    const float* other      = (const float*)d_in[2];
    const float* scene_desc = (const float*)d_in[3];
    const float* scene_sent = (const float*)d_in[4];
    const float* Ws         = (const float*)d_in[5];
    const float* bs         = (const float*)d_in[6];
    const float* W1         = (const float*)d_in[7];
    const float* b1         = (const float*)d_in[8];
    const float* W2         = (const float*)d_in[9];
    const float* b2         = (const float*)d_in[10];
    float* out = (float*)d_out;

    float* fused  = (float*)d_ws;         // 32*2304 floats
    float* final_ = fused + 32 * 2304;    // 32*3840 floats

    attn_small_kernel<<<dim3(32, 3), 256, 0, stream>>>(sentence, target, other,
                                                       scene_desc, scene_sent, fused);
    attn_fused_kernel<<<dim3(32, 9), 256, 0, stream>>>(fused, final_);
    shared_proj_kernel<<<dim3(32, 3), 512, 0, stream>>>(fused, Ws, bs, final_);
    mlp_kernel<<<32, 256, 0, stream>>>(final_, W1, b1, W2, b2, out);
}

// Round 2
// 138.056 us; speedup vs baseline: 2.7961x; 2.7961x over previous
//
#include <hip/hip_runtime.h>
#include <math.h>

#define LOG2E 1.44269504088896340736f

// fused layout per batch row: [sentence(768) | scene_context(768) | speaker_context(768)]
// final layout per batch row: [z(2304) | sentence_shared(512) | scene_shared(512) | speaker_shared(512)]

__global__ __launch_bounds__(256) void attn_small_kernel(
    const float* __restrict__ sentence,
    const float* __restrict__ target,
    const float* __restrict__ other,
    const float* __restrict__ scene_desc,
    const float* __restrict__ scene_sent,
    float* __restrict__ fused)
{
    const int b = blockIdx.x;
    const int part = blockIdx.y;   // 0: copy sentence, 1: scene ctx, 2: speaker ctx
    const int tid = threadIdx.x;

    if (part == 0) {
        for (int i = tid; i < 768; i += 256)
            fused[b * 2304 + i] = sentence[b * 768 + i];
        return;
    }

    __shared__ float kb[768];   // k * log2(e)
    __shared__ float vb[768];   // v
    const float* qp;
    const float* kp;
    const float* vp;
    if (part == 1) {            // scene_context = attn(q=scene_sent, k=scene_sent, v=scene_desc)
        qp = scene_sent + b * 768; kp = scene_sent + b * 768; vp = scene_desc + b * 768;
    } else {                    // speaker_context = attn(q=other, k=target, v=target)
        qp = other + b * 768;      kp = target + b * 768;     vp = target + b * 768;
    }
    for (int i = tid; i < 768; i += 256) {
        kb[i] = kp[i] * LOG2E;
        vb[i] = vp[i];
    }
    __syncthreads();

    float* out = fused + b * 2304 + part * 768;
    #pragma unroll
    for (int j = 0; j < 3; ++j) {
        const int s = tid + j * 256;
        const float q = qp[s];
        float n0 = 0.f, n1 = 0.f, n2 = 0.f, n3 = 0.f;
        float d0 = 0.f, d1 = 0.f, d2 = 0.f, d3 = 0.f;
        for (int t = 0; t < 768; t += 4) {
            float e0 = __builtin_amdgcn_exp2f(q * kb[t + 0]); n0 += e0 * vb[t + 0]; d0 += e0;
            float e1 = __builtin_amdgcn_exp2f(q * kb[t + 1]); n1 += e1 * vb[t + 1]; d1 += e1;
            float e2 = __builtin_amdgcn_exp2f(q * kb[t + 2]); n2 += e2 * vb[t + 2]; d2 += e2;
            float e3 = __builtin_amdgcn_exp2f(q * kb[t + 3]); n3 += e3 * vb[t + 3]; d3 += e3;
        }
        out[s] = ((n0 + n1) + (n2 + n3)) / ((d0 + d1) + (d2 + d3));
    }
}

__global__ __launch_bounds__(256) void attn_fused_kernel(
    const float* __restrict__ fused,
    float* __restrict__ final_)
{
    const int b = blockIdx.x;
    const int gy = blockIdx.y;     // row group: 9 groups of 256 rows
    const int tid = threadIdx.x;

    __shared__ float fb[2304];     // f * log2(e)  (exponent operand)
    __shared__ float vb[2304];     // f raw        (value operand)
    const float* f = fused + b * 2304;
    for (int i = tid; i < 2304; i += 256) {
        float x = f[i];
        vb[i] = x;
        fb[i] = x * LOG2E;
    }
    __syncthreads();

    const int s = gy * 256 + tid;
    const float q = vb[s];
    float n0 = 0.f, n1 = 0.f, n2 = 0.f, n3 = 0.f;
    float d0 = 0.f, d1 = 0.f, d2 = 0.f, d3 = 0.f;
    for (int t = 0; t < 2304; t += 4) {
        float e0 = __builtin_amdgcn_exp2f(q * fb[t + 0]); n0 += e0 * vb[t + 0]; d0 += e0;
        float e1 = __builtin_amdgcn_exp2f(q * fb[t + 1]); n1 += e1 * vb[t + 1]; d1 += e1;
        float e2 = __builtin_amdgcn_exp2f(q * fb[t + 2]); n2 += e2 * vb[t + 2]; d2 += e2;
        float e3 = __builtin_amdgcn_exp2f(q * fb[t + 3]); n3 += e3 * vb[t + 3]; d3 += e3;
    }
    final_[b * 3840 + s] = ((n0 + n1) + (n2 + n3)) / ((d0 + d1) + (d2 + d3));
}

// [B=32] x [768,512] projection, 3 input slices. One 1024-thread block per (b, slice).
// 8-way K-split inside the block: wave-pair g owns rows {g, g+8, g+16, ...}; each thread
// loads a float4 of 4 adjacent W columns -> 96 iterations/thread. LDS tree-reduce.
__global__ __launch_bounds__(1024) void shared_proj_kernel(
    const float* __restrict__ fused,
    const float* __restrict__ Ws,   // [768, 512]
    const float* __restrict__ bs,   // [512]
    float* __restrict__ final_)
{
    const int b = blockIdx.x;
    const int p = blockIdx.y;       // 0: sentence, 1: scene_ctx, 2: speaker_ctx
    const int tid = threadIdx.x;

    __shared__ float xb[768];
    __shared__ float red[8][512];
    const float* x = fused + b * 2304 + p * 768;
    if (tid < 768) xb[tid] = x[tid];
    __syncthreads();

    const int g = tid >> 7;         // 0..7 k-group (wave-uniform)
    const int q = tid & 127;        // column quad: cols 4q..4q+3
    const float4* __restrict__ Wv = (const float4*)Ws;   // [768][128]
    float ax = 0.f, ay = 0.f, az = 0.f, aw = 0.f;
    #pragma unroll 8
    for (int k = g; k < 768; k += 8) {
        const float xv = xb[k];
        const float4 w = Wv[k * 128 + q];
        ax += xv * w.x; ay += xv * w.y; az += xv * w.z; aw += xv * w.w;
    }
    red[g][q * 4 + 0] = ax;
    red[g][q * 4 + 1] = ay;
    red[g][q * 4 + 2] = az;
    red[g][q * 4 + 3] = aw;
    __syncthreads();

    if (tid < 512) {
        float s = bs[tid];
        #pragma unroll
        for (int g2 = 0; g2 < 8; ++g2) s += red[g2][tid];
        final_[b * 3840 + 2304 + p * 512 + tid] = s;
    }
}

// Whole MLP for one batch row per 1024-thread block (16 waves = 4/SIMD).
// Stage 1: h = relu(final @ W1 + b1), 16-way K-split (wave g owns rows [240g, 240g+240)),
//          float4 over 4 adjacent W1 columns -> 240 iterations/thread, LDS reduce.
// Stage 2: out = sigmoid(h @ W2 + b2), one wave per output column, shfl reduce.
__global__ __launch_bounds__(1024) void mlp_kernel(
    const float* __restrict__ final_,
    const float* __restrict__ W1,   // [3840, 256]
    const float* __restrict__ b1,   // [256]
    const float* __restrict__ W2,   // [256, 7]
    const float* __restrict__ b2,   // [7]
    float* __restrict__ out)        // [32, 7]
{
    const int b = blockIdx.x;
    const int tid = threadIdx.x;

    __shared__ float fb[3840];
    __shared__ float red[16][256];
    __shared__ float hb[256];
    const float* f = final_ + b * 3840;
    for (int i = tid; i < 3840; i += 1024) fb[i] = f[i];
    __syncthreads();

    const int g = tid >> 6;         // 0..15 k-group == wave id (wave-uniform LDS broadcast)
    const int q = tid & 63;         // column quad: cols 4q..4q+3
    const float4* __restrict__ Wv = (const float4*)W1;   // [3840][64]
    float ax = 0.f, ay = 0.f, az = 0.f, aw = 0.f;
    const int k0 = g * 240;
    #pragma unroll 8
    for (int k = k0; k < k0 + 240; ++k) {
        const float xv = fb[k];
        const float4 w = Wv[k * 64 + q];
        ax += xv * w.x; ay += xv * w.y; az += xv * w.z; aw += xv * w.w;
    }
    red[g][q * 4 + 0] = ax;
    red[g][q * 4 + 1] = ay;
    red[g][q * 4 + 2] = az;
    red[g][q * 4 + 3] = aw;
    __syncthreads();

    if (tid < 256) {
        float s = b1[tid];
        #pragma unroll
        for (int g2 = 0; g2 < 16; ++g2) s += red[g2][tid];
        hb[tid] = fmaxf(s, 0.f);
    }
    __syncthreads();

    const int w = tid >> 6;         // wave id
    const int lane = tid & 63;
    if (w < 7) {                    // one wave per output column
        float a = 0.f;
        #pragma unroll
        for (int c = lane; c < 256; c += 64)
            a += hb[c] * W2[c * 7 + w];
        #pragma unroll
        for (int off = 32; off > 0; off >>= 1)
            a += __shfl_down(a, off, 64);
        if (lane == 0)
            out[b * 7 + w] = 1.f / (1.f + __expf(-(a + b2[w])));
    }
}

extern "C" void kernel_launch(void* const* d_in, const int* in_sizes, int n_in,
                              void* d_out, int out_size, void* d_ws, size_t ws_size,
                              hipStream_t stream) {
    const float* sentence   = (const float*)d_in[0];
    const float* target     = (const float*)d_in[1];
    const float* other      = (const float*)d_in[2];
    const float* scene_desc = (const float*)d_in[3];
    const float* scene_sent = (const float*)d_in[4];
    const float* Ws         = (const float*)d_in[5];
    const float* bs         = (const float*)d_in[6];
    const float* W1         = (const float*)d_in[7];
    const float* b1         = (const float*)d_in[8];
    const float* W2         = (const float*)d_in[9];
    const float* b2         = (const float*)d_in[10];
    float* out = (float*)d_out;

    float* fused  = (float*)d_ws;         // 32*2304 floats
    float* final_ = fused + 32 * 2304;    // 32*3840 floats

    attn_small_kernel<<<dim3(32, 3), 256, 0, stream>>>(sentence, target, other,
                                                       scene_desc, scene_sent, fused);
    attn_fused_kernel<<<dim3(32, 9), 256, 0, stream>>>(fused, final_);
    shared_proj_kernel<<<dim3(32, 3), 1024, 0, stream>>>(fused, Ws, bs, final_);
    mlp_kernel<<<32, 1024, 0, stream>>>(final_, W1, b1, W2, b2, out);
}

// Round 3
// 85.411 us; speedup vs baseline: 4.5196x; 1.6164x over previous
//
#include <hip/hip_runtime.h>
#include <math.h>

#define LOG2E 1.44269504088896340736f

// ws layout:
//   ctx   [32][2][768]  : scene_context | speaker_context   (49152 floats)
//   final [32][3840]    : [z(2304) | sent_sh(512) | scene_sh(512) | spkr_sh(512)]
//   hpart [32][4][256]  : mlp stage-1 K-split partials

// Small attentions. grid (32, 2 parts, 3 rowgroups), 1024 threads.
// 4 sub-threads per row, each covering an interleaved quarter of t (float4 granular).
__global__ __launch_bounds__(1024) void attn_small_kernel(
    const float* __restrict__ target,
    const float* __restrict__ other,
    const float* __restrict__ scene_desc,
    const float* __restrict__ scene_sent,
    float* __restrict__ ctx)
{
    const int b = blockIdx.x;
    const int part = blockIdx.y;   // 0: scene ctx, 1: speaker ctx
    const int tid = threadIdx.x;

    const float* qp; const float* kp; const float* vp;
    if (part == 0) {  // scene_context = attn(q=scene_sent, k=scene_sent, v=scene_desc)
        qp = scene_sent + b * 768; kp = scene_sent + b * 768; vp = scene_desc + b * 768;
    } else {          // speaker_context = attn(q=other, k=target, v=target)
        qp = other + b * 768;      kp = target + b * 768;     vp = target + b * 768;
    }

    __shared__ float kb[768];
    __shared__ float vb[768];
    if (tid < 768) { kb[tid] = kp[tid]; vb[tid] = vp[tid]; }
    __syncthreads();

    const int r   = blockIdx.z * 256 + (tid >> 2);
    const int sub = tid & 3;
    const float qL = qp[r] * LOG2E;

    const float4* __restrict__ kv = (const float4*)kb;  // 192 float4
    const float4* __restrict__ vv = (const float4*)vb;
    float n0 = 0.f, n1 = 0.f, n2 = 0.f, n3 = 0.f;
    float d0 = 0.f, d1 = 0.f, d2 = 0.f, d3 = 0.f;
    #pragma unroll 4
    for (int i = 0; i < 48; ++i) {
        const int j = sub + 4 * i;
        const float4 k4 = kv[j];
        const float4 v4 = vv[j];
        float e0 = __builtin_amdgcn_exp2f(qL * k4.x); n0 += e0 * v4.x; d0 += e0;
        float e1 = __builtin_amdgcn_exp2f(qL * k4.y); n1 += e1 * v4.y; d1 += e1;
        float e2 = __builtin_amdgcn_exp2f(qL * k4.z); n2 += e2 * v4.z; d2 += e2;
        float e3 = __builtin_amdgcn_exp2f(qL * k4.w); n3 += e3 * v4.w; d3 += e3;
    }
    float num = (n0 + n1) + (n2 + n3);
    float den = (d0 + d1) + (d2 + d3);
    num += __shfl_xor(num, 1, 64); num += __shfl_xor(num, 2, 64);
    den += __shfl_xor(den, 1, 64); den += __shfl_xor(den, 2, 64);
    if (sub == 0)
        ctx[b * 1536 + part * 768 + r] = num / den;
}

// Fused self-attention over f = [sentence | scene_ctx | speaker_ctx] (q=k=v=f).
// grid (32, 9 rowgroups), 1024 threads; 4 sub-threads per row; single LDS array.
__global__ __launch_bounds__(1024) void attn_fused_kernel(
    const float* __restrict__ sentence,
    const float* __restrict__ ctx,
    float* __restrict__ final_)
{
    const int b = blockIdx.x;
    const int tid = threadIdx.x;

    __shared__ float vb[2304];
    if (tid < 768) vb[tid] = sentence[b * 768 + tid];
    for (int i = tid; i < 1536; i += 1024) vb[768 + i] = ctx[b * 1536 + i];
    __syncthreads();

    const int r   = blockIdx.y * 256 + (tid >> 2);
    const int sub = tid & 3;
    const float qL = vb[r] * LOG2E;

    const float4* __restrict__ fv = (const float4*)vb;  // 576 float4
    float n0 = 0.f, n1 = 0.f, n2 = 0.f, n3 = 0.f;
    float d0 = 0.f, d1 = 0.f, d2 = 0.f, d3 = 0.f;
    #pragma unroll 4
    for (int i = 0; i < 144; ++i) {
        const int j = sub + 4 * i;
        const float4 f4 = fv[j];
        float e0 = __builtin_amdgcn_exp2f(qL * f4.x); n0 += e0 * f4.x; d0 += e0;
        float e1 = __builtin_amdgcn_exp2f(qL * f4.y); n1 += e1 * f4.y; d1 += e1;
        float e2 = __builtin_amdgcn_exp2f(qL * f4.z); n2 += e2 * f4.z; d2 += e2;
        float e3 = __builtin_amdgcn_exp2f(qL * f4.w); n3 += e3 * f4.w; d3 += e3;
    }
    float num = (n0 + n1) + (n2 + n3);
    float den = (d0 + d1) + (d2 + d3);
    num += __shfl_xor(num, 1, 64); num += __shfl_xor(num, 2, 64);
    den += __shfl_xor(den, 1, 64); den += __shfl_xor(den, 2, 64);
    if (sub == 0)
        final_[b * 3840 + r] = num / den;
}

// [768,512] projection of 3 slices. grid (32,3), 1024 threads, 8-way K-split in block.
__global__ __launch_bounds__(1024) void shared_proj_kernel(
    const float* __restrict__ sentence,
    const float* __restrict__ ctx,
    const float* __restrict__ Ws,   // [768, 512]
    const float* __restrict__ bs,   // [512]
    float* __restrict__ final_)
{
    const int b = blockIdx.x;
    const int p = blockIdx.y;       // 0: sentence, 1: scene_ctx, 2: speaker_ctx
    const int tid = threadIdx.x;

    __shared__ float xb[768];
    __shared__ float red[8][512];
    const float* x = (p == 0) ? (sentence + b * 768) : (ctx + b * 1536 + (p - 1) * 768);
    if (tid < 768) xb[tid] = x[tid];
    __syncthreads();

    const int g = tid >> 7;         // 0..7 k-group (wave-pair uniform)
    const int q = tid & 127;        // column quad
    const float4* __restrict__ Wv = (const float4*)Ws;   // [768][128]
    float ax = 0.f, ay = 0.f, az = 0.f, aw = 0.f;
    #pragma unroll 8
    for (int k = g; k < 768; k += 8) {
        const float xv = xb[k];
        const float4 w = Wv[k * 128 + q];
        ax += xv * w.x; ay += xv * w.y; az += xv * w.z; aw += xv * w.w;
    }
    red[g][q * 4 + 0] = ax;
    red[g][q * 4 + 1] = ay;
    red[g][q * 4 + 2] = az;
    red[g][q * 4 + 3] = aw;
    __syncthreads();

    if (tid < 512) {
        float s = bs[tid];
        #pragma unroll
        for (int g2 = 0; g2 < 8; ++g2) s += red[g2][tid];
        final_[b * 3840 + 2304 + p * 512 + tid] = s;
    }
}

// MLP stage 1, K-split across blocks: grid (32,4), 1024 threads.
// Block c handles K-rows [960c, 960c+960): 16-wave split inside, writes partial to hpart.
__global__ __launch_bounds__(1024) void mlp_part_kernel(
    const float* __restrict__ final_,
    const float* __restrict__ W1,   // [3840, 256]
    float* __restrict__ hpart)      // [32][4][256]
{
    const int b = blockIdx.x;
    const int c = blockIdx.y;
    const int tid = threadIdx.x;
    const int base = c * 960;

    __shared__ float fb[960];
    __shared__ float red[16][256];
    if (tid < 960) fb[tid] = final_[b * 3840 + base + tid];
    __syncthreads();

    const int g = tid >> 6;         // wave id, 16 waves
    const int q = tid & 63;         // column quad
    const float4* __restrict__ Wv = (const float4*)W1;   // [3840][64]
    float ax = 0.f, ay = 0.f, az = 0.f, aw = 0.f;
    const int l0 = g * 60;
    #pragma unroll 4
    for (int kk = 0; kk < 60; ++kk) {
        const float xv = fb[l0 + kk];
        const float4 w = Wv[(base + l0 + kk) * 64 + q];
        ax += xv * w.x; ay += xv * w.y; az += xv * w.z; aw += xv * w.w;
    }
    red[g][q * 4 + 0] = ax;
    red[g][q * 4 + 1] = ay;
    red[g][q * 4 + 2] = az;
    red[g][q * 4 + 3] = aw;
    __syncthreads();

    if (tid < 256) {
        float s = 0.f;
        #pragma unroll
        for (int g2 = 0; g2 < 16; ++g2) s += red[g2][tid];
        hpart[(b * 4 + c) * 256 + tid] = s;
    }
}

// MLP tail: combine K-partials, relu, [256x7] head, sigmoid. grid 32, 512 threads.
__global__ __launch_bounds__(512) void mlp_tail_kernel(
    const float* __restrict__ hpart,
    const float* __restrict__ b1,
    const float* __restrict__ W2,   // [256, 7]
    const float* __restrict__ b2,
    float* __restrict__ out)        // [32, 7]
{
    const int b = blockIdx.x;
    const int tid = threadIdx.x;

    __shared__ float hb[256];
    if (tid < 256) {
        float s = b1[tid];
        #pragma unroll
        for (int c = 0; c < 4; ++c) s += hpart[(b * 4 + c) * 256 + tid];
        hb[tid] = fmaxf(s, 0.f);
    }
    __syncthreads();

    const int w = tid >> 6;
    const int lane = tid & 63;
    if (w < 7) {
        float a = 0.f;
        #pragma unroll
        for (int c = lane; c < 256; c += 64)
            a += hb[c] * W2[c * 7 + w];
        #pragma unroll
        for (int off = 32; off > 0; off >>= 1)
            a += __shfl_down(a, off, 64);
        if (lane == 0)
            out[b * 7 + w] = 1.f / (1.f + __expf(-(a + b2[w])));
    }
}

extern "C" void kernel_launch(void* const* d_in, const int* in_sizes, int n_in,
                              void* d_out, int out_size, void* d_ws, size_t ws_size,
                              hipStream_t stream) {
    const float* sentence   = (const float*)d_in[0];
    const float* target     = (const float*)d_in[1];
    const float* other      = (const float*)d_in[2];
    const float* scene_desc = (const float*)d_in[3];
    const float* scene_sent = (const float*)d_in[4];
    const float* Ws         = (const float*)d_in[5];
    const float* bs         = (const float*)d_in[6];
    const float* W1         = (const float*)d_in[7];
    const float* b1         = (const float*)d_in[8];
    const float* W2         = (const float*)d_in[9];
    const float* b2         = (const float*)d_in[10];
    float* out = (float*)d_out;

    float* ctx    = (float*)d_ws;             // 32*1536 floats
    float* final_ = ctx + 32 * 1536;          // 32*3840 floats
    float* hpart  = final_ + 32 * 3840;       // 32*4*256 floats

    attn_small_kernel<<<dim3(32, 2, 3), 1024, 0, stream>>>(target, other,
                                                           scene_desc, scene_sent, ctx);
    attn_fused_kernel<<<dim3(32, 9), 1024, 0, stream>>>(sentence, ctx, final_);
    shared_proj_kernel<<<dim3(32, 3), 1024, 0, stream>>>(sentence, ctx, Ws, bs, final_);
    mlp_part_kernel<<<dim3(32, 4), 1024, 0, stream>>>(final_, W1, hpart);
    mlp_tail_kernel<<<32, 512, 0, stream>>>(hpart, b1, W2, b2, out);
}

// Round 4
// 71.632 us; speedup vs baseline: 5.3890x; 1.1924x over previous
//
#include <hip/hip_runtime.h>
#include <math.h>

#define LOG2E 1.44269504088896340736f

// ws layout:
//   ctx   [32][2][768]  : scene_context | speaker_context   (49152 floats)
//   final [32][3840]    : [z(2304) | sent_sh(512) | scene_sh(512) | spkr_sh(512)]
//   hpart [32][8][256]  : mlp stage-1 K-split partials

// Small attentions. grid (32, 2 parts, 6 rowgroups of 128), 1024 threads.
// 8 sub-threads per row, each an interleaved eighth of t (float4 granular).
__global__ __launch_bounds__(1024) void attn_small_kernel(
    const float* __restrict__ target,
    const float* __restrict__ other,
    const float* __restrict__ scene_desc,
    const float* __restrict__ scene_sent,
    float* __restrict__ ctx)
{
    const int b = blockIdx.x;
    const int part = blockIdx.y;   // 0: scene ctx, 1: speaker ctx
    const int tid = threadIdx.x;

    const float* qp; const float* kp; const float* vp;
    if (part == 0) {  // scene_context = attn(q=scene_sent, k=scene_sent, v=scene_desc)
        qp = scene_sent + b * 768; kp = scene_sent + b * 768; vp = scene_desc + b * 768;
    } else {          // speaker_context = attn(q=other, k=target, v=target)
        qp = other + b * 768;      kp = target + b * 768;     vp = target + b * 768;
    }

    __shared__ float kb[768];
    __shared__ float vb[768];
    if (tid < 768) { kb[tid] = kp[tid]; vb[tid] = vp[tid]; }
    __syncthreads();

    const int r   = blockIdx.z * 128 + (tid >> 3);
    const int sub = tid & 7;
    const float qL = qp[r] * LOG2E;

    const float4* __restrict__ kv = (const float4*)kb;  // 192 float4
    const float4* __restrict__ vv = (const float4*)vb;
    float n0 = 0.f, n1 = 0.f, n2 = 0.f, n3 = 0.f;
    float d0 = 0.f, d1 = 0.f, d2 = 0.f, d3 = 0.f;
    #pragma unroll 4
    for (int i = 0; i < 24; ++i) {
        const int j = sub + 8 * i;
        const float4 k4 = kv[j];
        const float4 v4 = vv[j];
        float e0 = __builtin_amdgcn_exp2f(qL * k4.x); n0 += e0 * v4.x; d0 += e0;
        float e1 = __builtin_amdgcn_exp2f(qL * k4.y); n1 += e1 * v4.y; d1 += e1;
        float e2 = __builtin_amdgcn_exp2f(qL * k4.z); n2 += e2 * v4.z; d2 += e2;
        float e3 = __builtin_amdgcn_exp2f(qL * k4.w); n3 += e3 * v4.w; d3 += e3;
    }
    float num = (n0 + n1) + (n2 + n3);
    float den = (d0 + d1) + (d2 + d3);
    num += __shfl_xor(num, 1, 64); num += __shfl_xor(num, 2, 64); num += __shfl_xor(num, 4, 64);
    den += __shfl_xor(den, 1, 64); den += __shfl_xor(den, 2, 64); den += __shfl_xor(den, 4, 64);
    if (sub == 0)
        ctx[b * 1536 + part * 768 + r] = num / den;
}

// Fused self-attention over f = [sentence | scene_ctx | speaker_ctx] (q=k=v=f).
// grid (32, 18 rowgroups of 128), 1024 threads; 8 sub-threads per row; single LDS array.
__global__ __launch_bounds__(1024) void attn_fused_kernel(
    const float* __restrict__ sentence,
    const float* __restrict__ ctx,
    float* __restrict__ final_)
{
    const int b = blockIdx.x;
    const int tid = threadIdx.x;

    __shared__ float vb[2304];
    if (tid < 768) vb[tid] = sentence[b * 768 + tid];
    for (int i = tid; i < 1536; i += 1024) vb[768 + i] = ctx[b * 1536 + i];
    __syncthreads();

    const int r   = blockIdx.y * 128 + (tid >> 3);
    const int sub = tid & 7;
    const float qL = vb[r] * LOG2E;

    const float4* __restrict__ fv = (const float4*)vb;  // 576 float4
    float n0 = 0.f, n1 = 0.f, n2 = 0.f, n3 = 0.f;
    float d0 = 0.f, d1 = 0.f, d2 = 0.f, d3 = 0.f;
    #pragma unroll 4
    for (int i = 0; i < 72; ++i) {
        const int j = sub + 8 * i;
        const float4 f4 = fv[j];
        float e0 = __builtin_amdgcn_exp2f(qL * f4.x); n0 += e0 * f4.x; d0 += e0;
        float e1 = __builtin_amdgcn_exp2f(qL * f4.y); n1 += e1 * f4.y; d1 += e1;
        float e2 = __builtin_amdgcn_exp2f(qL * f4.z); n2 += e2 * f4.z; d2 += e2;
        float e3 = __builtin_amdgcn_exp2f(qL * f4.w); n3 += e3 * f4.w; d3 += e3;
    }
    float num = (n0 + n1) + (n2 + n3);
    float den = (d0 + d1) + (d2 + d3);
    num += __shfl_xor(num, 1, 64); num += __shfl_xor(num, 2, 64); num += __shfl_xor(num, 4, 64);
    den += __shfl_xor(den, 1, 64); den += __shfl_xor(den, 2, 64); den += __shfl_xor(den, 4, 64);
    if (sub == 0)
        final_[b * 3840 + r] = num / den;
}

// [768,512] projection of 3 slices. grid (32,3), 1024 threads, 8-way K-split in block.
__global__ __launch_bounds__(1024) void shared_proj_kernel(
    const float* __restrict__ sentence,
    const float* __restrict__ ctx,
    const float* __restrict__ Ws,   // [768, 512]
    const float* __restrict__ bs,   // [512]
    float* __restrict__ final_)
{
    const int b = blockIdx.x;
    const int p = blockIdx.y;       // 0: sentence, 1: scene_ctx, 2: speaker_ctx
    const int tid = threadIdx.x;

    __shared__ float xb[768];
    __shared__ float red[8][512];
    const float* x = (p == 0) ? (sentence + b * 768) : (ctx + b * 1536 + (p - 1) * 768);
    if (tid < 768) xb[tid] = x[tid];
    __syncthreads();

    const int g = tid >> 7;         // 0..7 k-group (wave-pair uniform)
    const int q = tid & 127;        // column quad
    const float4* __restrict__ Wv = (const float4*)Ws;   // [768][128]
    float ax = 0.f, ay = 0.f, az = 0.f, aw = 0.f;
    #pragma unroll 8
    for (int k = g; k < 768; k += 8) {
        const float xv = xb[k];
        const float4 w = Wv[k * 128 + q];
        ax += xv * w.x; ay += xv * w.y; az += xv * w.z; aw += xv * w.w;
    }
    red[g][q * 4 + 0] = ax;
    red[g][q * 4 + 1] = ay;
    red[g][q * 4 + 2] = az;
    red[g][q * 4 + 3] = aw;
    __syncthreads();

    if (tid < 512) {
        float s = bs[tid];
        #pragma unroll
        for (int g2 = 0; g2 < 8; ++g2) s += red[g2][tid];
        final_[b * 3840 + 2304 + p * 512 + tid] = s;
    }
}

// MLP stage 1, K-split across blocks: grid (32,8), 1024 threads.
// Block c handles K-rows [480c, 480c+480): 16-wave split inside, writes partial to hpart.
__global__ __launch_bounds__(1024) void mlp_part_kernel(
    const float* __restrict__ final_,
    const float* __restrict__ W1,   // [3840, 256]
    float* __restrict__ hpart)      // [32][8][256]
{
    const int b = blockIdx.x;
    const int c = blockIdx.y;
    const int tid = threadIdx.x;
    const int base = c * 480;

    __shared__ float fb[480];
    __shared__ float red[16][256];
    if (tid < 480) fb[tid] = final_[b * 3840 + base + tid];
    __syncthreads();

    const int g = tid >> 6;         // wave id, 16 waves
    const int q = tid & 63;         // column quad
    const float4* __restrict__ Wv = (const float4*)W1;   // [3840][64]
    float ax = 0.f, ay = 0.f, az = 0.f, aw = 0.f;
    const int l0 = g * 30;
    #pragma unroll 5
    for (int kk = 0; kk < 30; ++kk) {
        const float xv = fb[l0 + kk];
        const float4 w = Wv[(base + l0 + kk) * 64 + q];
        ax += xv * w.x; ay += xv * w.y; az += xv * w.z; aw += xv * w.w;
    }
    red[g][q * 4 + 0] = ax;
    red[g][q * 4 + 1] = ay;
    red[g][q * 4 + 2] = az;
    red[g][q * 4 + 3] = aw;
    __syncthreads();

    if (tid < 256) {
        float s = 0.f;
        #pragma unroll
        for (int g2 = 0; g2 < 16; ++g2) s += red[g2][tid];
        hpart[(b * 8 + c) * 256 + tid] = s;
    }
}

// MLP tail: combine K-partials, relu, [256x7] head, sigmoid. grid 32, 512 threads.
__global__ __launch_bounds__(512) void mlp_tail_kernel(
    const float* __restrict__ hpart,
    const float* __restrict__ b1,
    const float* __restrict__ W2,   // [256, 7]
    const float* __restrict__ b2,
    float* __restrict__ out)        // [32, 7]
{
    const int b = blockIdx.x;
    const int tid = threadIdx.x;

    __shared__ float hb[256];
    if (tid < 256) {
        float s = b1[tid];
        #pragma unroll
        for (int c = 0; c < 8; ++c) s += hpart[(b * 8 + c) * 256 + tid];
        hb[tid] = fmaxf(s, 0.f);
    }
    __syncthreads();

    const int w = tid >> 6;
    const int lane = tid & 63;
    if (w < 7) {
        float a = 0.f;
        #pragma unroll
        for (int c = lane; c < 256; c += 64)
            a += hb[c] * W2[c * 7 + w];
        #pragma unroll
        for (int off = 32; off > 0; off >>= 1)
            a += __shfl_down(a, off, 64);
        if (lane == 0)
            out[b * 7 + w] = 1.f / (1.f + __expf(-(a + b2[w])));
    }
}

extern "C" void kernel_launch(void* const* d_in, const int* in_sizes, int n_in,
                              void* d_out, int out_size, void* d_ws, size_t ws_size,
                              hipStream_t stream) {
    const float* sentence   = (const float*)d_in[0];
    const float* target     = (const float*)d_in[1];
    const float* other      = (const float*)d_in[2];
    const float* scene_desc = (const float*)d_in[3];
    const float* scene_sent = (const float*)d_in[4];
    const float* Ws         = (const float*)d_in[5];
    const float* bs         = (const float*)d_in[6];
    const float* W1         = (const float*)d_in[7];
    const float* b1         = (const float*)d_in[8];
    const float* W2         = (const float*)d_in[9];
    const float* b2         = (const float*)d_in[10];
    float* out = (float*)d_out;

    float* ctx    = (float*)d_ws;             // 32*1536 floats
    float* final_ = ctx + 32 * 1536;          // 32*3840 floats
    float* hpart  = final_ + 32 * 3840;       // 32*8*256 floats

    attn_small_kernel<<<dim3(32, 2, 6), 1024, 0, stream>>>(target, other,
                                                           scene_desc, scene_sent, ctx);
    attn_fused_kernel<<<dim3(32, 18), 1024, 0, stream>>>(sentence, ctx, final_);
    shared_proj_kernel<<<dim3(32, 3), 1024, 0, stream>>>(sentence, ctx, Ws, bs, final_);
    mlp_part_kernel<<<dim3(32, 8), 1024, 0, stream>>>(final_, W1, hpart);
    mlp_tail_kernel<<<32, 512, 0, stream>>>(hpart, b1, W2, b2, out);
}